// Round 4
// baseline (256.112 us; speedup 1.0000x reference)
//
#include <hip/hip_runtime.h>

// RNN_53214644797476: out = tanh(X @ W^T + hs @ H^T), hs never updated.
// => one GEMM [32768,1024]x[1024,1024]^T + tiny h_term + tanh epilogue.
// Round 4: round-1's proven 128x128/4-wave/gload_lds structure, upgraded:
//  (a) cvt kernels PRE-SWIZZLE Xbf/Wbf (slot s' = s ^ ((row>>1)&3) within
//      64B groups) -> linear gload_lds dest + XOR on ds_read = 0 bank conflicts
//  (b) 3-LDS-buffer 1-barrier K-loop with counted vmcnt(4) (never 0 in-loop)
//  (c) setprio(1) around the MFMA cluster

typedef __bf16 bf16x8 __attribute__((ext_vector_type(8)));
typedef float f32x4 __attribute__((ext_vector_type(4)));
typedef unsigned short ushort8 __attribute__((ext_vector_type(8)));

constexpr int M_TOT = 32768;  // SEQ*BATCH
constexpr int K_D = 1024;
constexpr int N_D = 1024;
constexpr int NTK = K_D / 32;       // 32 K-tiles
constexpr int TILE = 128 * 32;      // ushorts per LDS tile (8 KiB)

__device__ __forceinline__ void async16(const void* g, void* l) {
  __builtin_amdgcn_global_load_lds(
      (const __attribute__((address_space(1))) unsigned int*)g,
      (__attribute__((address_space(3))) unsigned int*)l, 16, 0, 0);
}

__device__ __forceinline__ unsigned short f2bf(float f) {
  unsigned int u = __float_as_uint(f);
  u += 0x7FFFu + ((u >> 16) & 1u);  // round-to-nearest-even
  return (unsigned short)(u >> 16);
}

// ---- f32 -> bf16 conversion + slot pre-swizzle ----
// Thread i handles one 16B output slot: row = i>>7, slot st = i&127.
// Stored slot position: (st & ~3) | ((st&3) ^ ((row>>1)&3)).
__global__ __launch_bounds__(256) void cvt_swz(
    const float* __restrict__ in, unsigned short* __restrict__ out, int nslot) {
  int stride = gridDim.x * blockDim.x;
  for (int i = blockIdx.x * blockDim.x + threadIdx.x; i < nslot; i += stride) {
    int row = i >> 7, st = i & 127;
    const float4* p = reinterpret_cast<const float4*>(in + (size_t)i * 8);
    float4 a = p[0], b = p[1];
    ushort8 v;
    v[0] = f2bf(a.x); v[1] = f2bf(a.y); v[2] = f2bf(a.z); v[3] = f2bf(a.w);
    v[4] = f2bf(b.x); v[5] = f2bf(b.y); v[6] = f2bf(b.z); v[7] = f2bf(b.w);
    int sd = (st & ~3) | ((st & 3) ^ ((row >> 1) & 3));
    *reinterpret_cast<ushort8*>(out + (size_t)row * 1024 + sd * 8) = v;
  }
}

// ---- h_term[b][h] = sum_k hs[b][k] * H[h][k] ; one block per h ----
__global__ __launch_bounds__(256) void hterm_kernel(
    const float* __restrict__ hs, const float* __restrict__ Hm,
    float* __restrict__ ht) {
  int h = blockIdx.x;
  __shared__ float Hrow[1024];
  for (int i = threadIdx.x; i < 1024; i += 256)
    Hrow[i] = Hm[(size_t)h * 1024 + i];
  __syncthreads();
  int w = threadIdx.x >> 6, l = threadIdx.x & 63;
  for (int b = w; b < 64; b += 4) {
    float s = 0.f;
    const float* hb = hs + (size_t)b * 1024;
    for (int k = l; k < 1024; k += 64) s += hb[k] * Hrow[k];
#pragma unroll
    for (int off = 32; off > 0; off >>= 1) s += __shfl_down(s, off, 64);
    if (l == 0) ht[b * 1024 + h] = s;
  }
}

// ---- main GEMM: C = tanh(A[M,K](bf16,pre-swz) . B[N,K](bf16,pre-swz)^T + ht) ----
__global__ __launch_bounds__(256, 3) void gemm_tanh(
    const unsigned short* __restrict__ A, const unsigned short* __restrict__ B,
    const float* __restrict__ ht, float* __restrict__ out0,
    float* __restrict__ out1) {
  __shared__ unsigned short As[3][TILE];  // 24 KiB
  __shared__ unsigned short Bs[3][TILE];  // 24 KiB

  // XCD-bijective swizzle (nwg = 2048 % 8 == 0); A-panel sharers co-XCD.
  int bid = blockIdx.x;
  int swz = (bid & 7) * 256 + (bid >> 3);
  int bm = swz >> 3;  // 0..255
  int bn = swz & 7;   // 0..7

  int tid = threadIdx.x;
  int lane = tid & 63, wid = tid >> 6;
  int wr = wid >> 1, wc = wid & 1;
  int fr = lane & 15, kq = lane >> 4;

  // Staging: chunk c in [0,1024) -> tile row c>>2, slot c&3; LDS linear c*16B.
  // Global source is pre-swizzled, so the source address is LINEAR too.
  int c1 = tid + 256;
  const unsigned short* gA0 = A + (size_t)(bm * 128 + (tid >> 2)) * 1024 + (tid & 3) * 8;
  const unsigned short* gA1 = A + (size_t)(bm * 128 + (c1 >> 2)) * 1024 + (c1 & 3) * 8;
  const unsigned short* gB0 = B + (size_t)(bn * 128 + (tid >> 2)) * 1024 + (tid & 3) * 8;
  const unsigned short* gB1 = B + (size_t)(bn * 128 + (c1 >> 2)) * 1024 + (c1 & 3) * 8;

  f32x4 acc[4][4] = {};

#define STAGE(kt, buf)                              \
  {                                                 \
    async16(gA0 + (kt) * 32, &As[buf][tid * 8]);    \
    async16(gA1 + (kt) * 32, &As[buf][c1 * 8]);     \
    async16(gB0 + (kt) * 32, &Bs[buf][tid * 8]);    \
    async16(gB1 + (kt) * 32, &Bs[buf][c1 * 8]);     \
  }

  // Prologue: stage tiles 0 and 1; wait tile 0 only (counted).
  STAGE(0, 0);
  STAGE(1, 1);
  asm volatile("s_waitcnt vmcnt(4)" ::: "memory");
  __builtin_amdgcn_s_barrier();
  asm volatile("" ::: "memory");

  for (int kt = 0; kt < NTK; ++kt) {
    const int cur = kt % 3;
    if (kt + 2 < NTK) STAGE(kt + 2, (kt + 2) % 3);

    bf16x8 af[4], bg[4];
#pragma unroll
    for (int mi = 0; mi < 4; ++mi) {
      int ra = wr * 64 + mi * 16 + fr;
      af[mi] = *reinterpret_cast<const bf16x8*>(
          &As[cur][ra * 32 + (kq ^ ((ra >> 1) & 3)) * 8]);
    }
#pragma unroll
    for (int ni = 0; ni < 4; ++ni) {
      int rb = wc * 64 + ni * 16 + fr;
      bg[ni] = *reinterpret_cast<const bf16x8*>(
          &Bs[cur][rb * 32 + (kq ^ ((rb >> 1) & 3)) * 8]);
    }
    __builtin_amdgcn_s_setprio(1);
#pragma unroll
    for (int mi = 0; mi < 4; ++mi)
#pragma unroll
      for (int ni = 0; ni < 4; ++ni)
        acc[mi][ni] = __builtin_amdgcn_mfma_f32_16x16x32_bf16(
            af[mi], bg[ni], acc[mi][ni], 0, 0, 0);
    __builtin_amdgcn_s_setprio(0);

    if (kt + 1 < NTK) {
      // Ensure tile kt+1 resident; keep tile kt+2's 4 loads in flight.
      if (kt + 2 < NTK)
        asm volatile("s_waitcnt vmcnt(4)" ::: "memory");
      else
        asm volatile("s_waitcnt vmcnt(0)" ::: "memory");
      __builtin_amdgcn_s_barrier();
      asm volatile("" ::: "memory");
    }
  }

  // Epilogue: y = tanh(acc + ht[m%64][n]); out0 always, out1 for last 64 rows.
  const int nbase = bn * 128 + wc * 64;
#pragma unroll
  for (int mi = 0; mi < 4; ++mi) {
#pragma unroll
    for (int r = 0; r < 4; ++r) {
      int mloc = wr * 64 + mi * 16 + kq * 4 + r;
      size_t m = (size_t)bm * 128 + mloc;
      int b = mloc & 63;
#pragma unroll
      for (int ni = 0; ni < 4; ++ni) {
        int n = nbase + ni * 16 + fr;
        float x = acc[mi][ni][r] + ht[b * 1024 + n];
        float e = __expf(2.0f * x);
        float y = 1.0f - 2.0f / (e + 1.0f);  // tanh(x), safe at +-inf
        out0[m * 1024 + n] = y;
        if (m >= (size_t)(M_TOT - 64))
          out1[(m - (M_TOT - 64)) * 1024 + n] = y;
      }
    }
  }
#undef STAGE
}

extern "C" void kernel_launch(void* const* d_in, const int* in_sizes, int n_in,
                              void* d_out, int out_size, void* d_ws,
                              size_t ws_size, hipStream_t stream) {
  (void)in_sizes; (void)n_in; (void)out_size; (void)ws_size;
  const float* X  = (const float*)d_in[0];  // [512,64,1024] = [32768,1024]
  const float* hs = (const float*)d_in[1];  // [64,1024]
  const float* W  = (const float*)d_in[2];  // [1024,1024]
  const float* Hm = (const float*)d_in[3];  // [1024,1024]
  float* out0 = (float*)d_out;               // [32768,1024]
  float* out1 = out0 + (size_t)M_TOT * N_D;  // [64,1024]

  // ws layout: Xbf (64 MiB) | Wbf (2 MiB) | hterm (256 KiB)
  unsigned short* Xbf = (unsigned short*)d_ws;
  unsigned short* Wbf = Xbf + (size_t)M_TOT * K_D;
  float* hterm = (float*)(Wbf + (size_t)N_D * K_D);

  cvt_swz<<<2048, 256, 0, stream>>>(X, Xbf, M_TOT * K_D / 8);
  cvt_swz<<<512, 256, 0, stream>>>(W, Wbf, N_D * K_D / 8);
  hterm_kernel<<<1024, 256, 0, stream>>>(hs, Hm, hterm);
  gemm_tanh<<<(M_TOT / 128) * (N_D / 128), 256, 0, stream>>>(Xbf, Wbf, hterm,
                                                             out0, out1);
}

// Round 5
// 228.301 us; speedup vs baseline: 1.1218x; 1.1218x over previous
//
#include <hip/hip_runtime.h>

// RNN_53214644797476: out = tanh(X @ W^T + hs @ H^T), hs never updated.
// => one GEMM [32768,1024]x[1024,1024]^T + tiny h_term + tanh epilogue.
// Round 5: round-1's measured-best GEMM regime (128x128, 4 waves, single
// LDS buffer 16 KB, 2 barriers/K-step, gload_lds staging) + two free deltas:
//   (a) pre-swizzled Xbf/Wbf (slot s^=(row>>1)&3 in 64B groups) -> 0 bank
//       conflicts on ds_read_b128 (verified round 4), linear staging addrs
//   (b) __launch_bounds__(256,4) for 4 blocks/CU
// and ONE merged prep kernel (cvtX | cvtW | hterm by block range) to cut
// two kernel-launch gaps (~12-15 us each).

typedef __bf16 bf16x8 __attribute__((ext_vector_type(8)));
typedef float f32x4 __attribute__((ext_vector_type(4)));
typedef unsigned short ushort8 __attribute__((ext_vector_type(8)));

constexpr int M_TOT = 32768;  // SEQ*BATCH
constexpr int K_D = 1024;
constexpr int N_D = 1024;
constexpr int NTK = K_D / 32;  // 32 K-tiles of BK=32

__device__ __forceinline__ void async16(const void* g, void* l) {
  __builtin_amdgcn_global_load_lds(
      (const __attribute__((address_space(1))) unsigned int*)g,
      (__attribute__((address_space(3))) unsigned int*)l, 16, 0, 0);
}

__device__ __forceinline__ unsigned short f2bf(float f) {
  unsigned int u = __float_as_uint(f);
  u += 0x7FFFu + ((u >> 16) & 1u);  // round-to-nearest-even
  return (unsigned short)(u >> 16);
}

// Convert one 16B slot (8 f32 -> 8 bf16) and store with slot pre-swizzle:
// row = i>>7, slot st = i&127, stored slot = (st&~3) | ((st&3)^((row>>1)&3)).
__device__ __forceinline__ void cvt_one(const float* __restrict__ in,
                                        unsigned short* __restrict__ out,
                                        int i) {
  int row = i >> 7, st = i & 127;
  const float4* p = reinterpret_cast<const float4*>(in + (size_t)i * 8);
  float4 a = p[0], b = p[1];
  ushort8 v;
  v[0] = f2bf(a.x); v[1] = f2bf(a.y); v[2] = f2bf(a.z); v[3] = f2bf(a.w);
  v[4] = f2bf(b.x); v[5] = f2bf(b.y); v[6] = f2bf(b.z); v[7] = f2bf(b.w);
  int sd = (st & ~3) | ((st & 3) ^ ((row >> 1) & 3));
  *reinterpret_cast<ushort8*>(out + (size_t)row * 1024 + sd * 8) = v;
}

// ---- merged prep: blocks [0,2048) cvt X; [2048,2560) cvt W; [2560,3584) hterm
constexpr int PREP_XBLK = 2048, PREP_WBLK = 512, PREP_HBLK = 1024;
constexpr int PREP_GRID = PREP_XBLK + PREP_WBLK + PREP_HBLK;

__global__ __launch_bounds__(256) void prep_kernel(
    const float* __restrict__ X, unsigned short* __restrict__ Xbf,
    const float* __restrict__ W, unsigned short* __restrict__ Wbf,
    const float* __restrict__ hs, const float* __restrict__ Hm,
    float* __restrict__ ht) {
  __shared__ float Hrow[1024];
  int b = blockIdx.x;
  if (b < PREP_XBLK) {
    // X: 32768*1024/8 = 4,194,304 slots over 524,288 threads -> 8 iters
    const int nslot = M_TOT * K_D / 8;
    const int stride = PREP_XBLK * 256;
    for (int i = b * 256 + (int)threadIdx.x; i < nslot; i += stride)
      cvt_one(X, Xbf, i);
  } else if (b < PREP_XBLK + PREP_WBLK) {
    // W: 1024*1024/8 = 131,072 slots over 131,072 threads -> 1 iter
    int i = (b - PREP_XBLK) * 256 + (int)threadIdx.x;
    cvt_one(W, Wbf, i);
  } else {
    // h_term[b][h] = sum_k hs[b][k] * H[h][k]; one block per h
    int h = b - (PREP_XBLK + PREP_WBLK);
    for (int i = threadIdx.x; i < 1024; i += 256)
      Hrow[i] = Hm[(size_t)h * 1024 + i];
    __syncthreads();
    int w = threadIdx.x >> 6, l = threadIdx.x & 63;
    for (int bb = w; bb < 64; bb += 4) {
      float s = 0.f;
      const float* hb = hs + (size_t)bb * 1024;
      for (int k = l; k < 1024; k += 64) s += hb[k] * Hrow[k];
#pragma unroll
      for (int off = 32; off > 0; off >>= 1) s += __shfl_down(s, off, 64);
      if (l == 0) ht[bb * 1024 + h] = s;
    }
  }
}

// ---- main GEMM: C = tanh(A[M,K](bf16,pre-swz) . B[N,K](bf16,pre-swz)^T + ht)
__global__ __launch_bounds__(256, 4) void gemm_tanh(
    const unsigned short* __restrict__ A, const unsigned short* __restrict__ B,
    const float* __restrict__ ht, float* __restrict__ out0,
    float* __restrict__ out1) {
  __shared__ unsigned short As[128 * 32];  // 8 KiB
  __shared__ unsigned short Bs[128 * 32];  // 8 KiB

  // XCD-bijective swizzle (nwg = 2048 % 8 == 0); A-panel sharers co-XCD.
  int bid = blockIdx.x;
  int swz = (bid & 7) * 256 + (bid >> 3);
  int bm = swz >> 3;  // 0..255
  int bn = swz & 7;   // 0..7

  int tid = threadIdx.x;
  int lane = tid & 63, wid = tid >> 6;
  int wr = wid >> 1, wc = wid & 1;
  int fr = lane & 15, kq = lane >> 4;

  // Staging: chunk c in [0,1024) -> row c>>2, stored slot c&3; LDS linear.
  // Source memory is pre-swizzled, so global addresses are linear too.
  int c1 = tid + 256;
  const unsigned short* gA0 =
      A + (size_t)(bm * 128 + (tid >> 2)) * 1024 + (tid & 3) * 8;
  const unsigned short* gA1 =
      A + (size_t)(bm * 128 + (c1 >> 2)) * 1024 + (c1 & 3) * 8;
  const unsigned short* gB0 =
      B + (size_t)(bn * 128 + (tid >> 2)) * 1024 + (tid & 3) * 8;
  const unsigned short* gB1 =
      B + (size_t)(bn * 128 + (c1 >> 2)) * 1024 + (c1 & 3) * 8;

  f32x4 acc[4][4] = {};

  for (int ks = 0; ks < K_D; ks += 32) {
    async16(gA0 + ks, &As[tid * 8]);
    async16(gA1 + ks, &As[c1 * 8]);
    async16(gB0 + ks, &Bs[tid * 8]);
    async16(gB1 + ks, &Bs[c1 * 8]);
    __syncthreads();  // drains vmcnt+lgkmcnt before LDS reads

    bf16x8 af[4], bg[4];
#pragma unroll
    for (int mi = 0; mi < 4; ++mi) {
      int ra = wr * 64 + mi * 16 + fr;
      af[mi] = *reinterpret_cast<const bf16x8*>(
          &As[ra * 32 + (kq ^ ((ra >> 1) & 3)) * 8]);
    }
#pragma unroll
    for (int ni = 0; ni < 4; ++ni) {
      int rb = wc * 64 + ni * 16 + fr;
      bg[ni] = *reinterpret_cast<const bf16x8*>(
          &Bs[rb * 32 + (kq ^ ((rb >> 1) & 3)) * 8]);
    }
#pragma unroll
    for (int mi = 0; mi < 4; ++mi)
#pragma unroll
      for (int ni = 0; ni < 4; ++ni)
        acc[mi][ni] = __builtin_amdgcn_mfma_f32_16x16x32_bf16(
            af[mi], bg[ni], acc[mi][ni], 0, 0, 0);
    __syncthreads();  // before next stage overwrites LDS
  }

  // Epilogue: y = tanh(acc + ht[m%64][n]); out0 always, out1 for last 64 rows.
  const int nbase = bn * 128 + wc * 64;
#pragma unroll
  for (int mi = 0; mi < 4; ++mi) {
#pragma unroll
    for (int r = 0; r < 4; ++r) {
      int mloc = wr * 64 + mi * 16 + kq * 4 + r;
      size_t m = (size_t)bm * 128 + mloc;
      int b = mloc & 63;
#pragma unroll
      for (int ni = 0; ni < 4; ++ni) {
        int n = nbase + ni * 16 + fr;
        float x = acc[mi][ni][r] + ht[b * 1024 + n];
        float e = __expf(2.0f * x);
        float y = 1.0f - 2.0f / (e + 1.0f);  // tanh(x), safe at +-inf
        out0[m * 1024 + n] = y;
        if (m >= (size_t)(M_TOT - 64))
          out1[(m - (M_TOT - 64)) * 1024 + n] = y;
      }
    }
  }
}

extern "C" void kernel_launch(void* const* d_in, const int* in_sizes, int n_in,
                              void* d_out, int out_size, void* d_ws,
                              size_t ws_size, hipStream_t stream) {
  (void)in_sizes; (void)n_in; (void)out_size; (void)ws_size;
  const float* X  = (const float*)d_in[0];  // [512,64,1024] = [32768,1024]
  const float* hs = (const float*)d_in[1];  // [64,1024]
  const float* W  = (const float*)d_in[2];  // [1024,1024]
  const float* Hm = (const float*)d_in[3];  // [1024,1024]
  float* out0 = (float*)d_out;               // [32768,1024]
  float* out1 = out0 + (size_t)M_TOT * N_D;  // [64,1024]

  // ws layout: Xbf (64 MiB) | Wbf (2 MiB) | hterm (256 KiB)
  unsigned short* Xbf = (unsigned short*)d_ws;
  unsigned short* Wbf = Xbf + (size_t)M_TOT * K_D;
  float* hterm = (float*)(Wbf + (size_t)N_D * K_D);

  prep_kernel<<<PREP_GRID, 256, 0, stream>>>(X, Xbf, W, Wbf, hs, Hm, hterm);
  gemm_tanh<<<(M_TOT / 128) * (N_D / 128), 256, 0, stream>>>(Xbf, Wbf, hterm,
                                                             out0, out1);
}

// Round 6
// 161.867 us; speedup vs baseline: 1.5822x; 1.4104x over previous
//
#include <hip/hip_runtime.h>

// RNN_53214644797476: out = tanh(X @ W^T + hs @ H^T), hs never updated.
// => one GEMM [32768,1024]x[1024,1024]^T + tiny h_term + tanh epilogue.
// Round 6: GEMM kept byte-for-byte from round 5 (measured ~70 us: pre-swz
// inputs -> 0 bank conflicts, 4 blocks/CU, 2-barrier loop). Prep rebuilt:
// one work-item per thread (no grid-stride loops -> full MLP/TLP): each
// thread reads ONE float4 (unit-stride) and stores ONE swizzled 8B ushort4;
// hterm uses float4-vectorized dot with unrolled loads. R5's prep was 150 us
// at 1.4 TB/s with VGPR=12 -- serialized latency-bound loops.

typedef __bf16 bf16x8 __attribute__((ext_vector_type(8)));
typedef float f32x4 __attribute__((ext_vector_type(4)));
typedef unsigned short us4 __attribute__((ext_vector_type(4)));

constexpr int M_TOT = 32768;  // SEQ*BATCH
constexpr int K_D = 1024;
constexpr int N_D = 1024;

__device__ __forceinline__ void async16(const void* g, void* l) {
  __builtin_amdgcn_global_load_lds(
      (const __attribute__((address_space(1))) unsigned int*)g,
      (__attribute__((address_space(3))) unsigned int*)l, 16, 0, 0);
}

__device__ __forceinline__ unsigned short f2bf(float f) {
  unsigned int u = __float_as_uint(f);
  u += 0x7FFFu + ((u >> 16) & 1u);  // round-to-nearest-even
  return (unsigned short)(u >> 16);
}

// ---- merged prep ----
// blocks [0, XBLK): X cvt, one float4 (= half of a 16B slot) per thread
// blocks [XBLK, XBLK+WBLK): W cvt, same
// blocks [XBLK+WBLK, +HBLK): h_term, one block per h
// Slot pre-swizzle (must match gemm's read XOR): 16B slot st of row ->
// stored at sd = (st&~3) | ((st&3) ^ ((row>>1)&3)).
constexpr int PREP_XBLK = M_TOT * K_D / 4 / 256;  // 32768
constexpr int PREP_WBLK = N_D * K_D / 4 / 256;    // 1024
constexpr int PREP_HBLK = 1024;
constexpr int PREP_GRID = PREP_XBLK + PREP_WBLK + PREP_HBLK;

__global__ __launch_bounds__(256) void prep_kernel(
    const float* __restrict__ X, unsigned short* __restrict__ Xbf,
    const float* __restrict__ W, unsigned short* __restrict__ Wbf,
    const float* __restrict__ hs, const float* __restrict__ Hm,
    float* __restrict__ ht) {
  __shared__ float4 Hrow4[256];
  const int b = blockIdx.x;
  const int tid = threadIdx.x;

  if (b < PREP_XBLK + PREP_WBLK) {
    const float* in = (b < PREP_XBLK) ? X : W;
    unsigned short* out = (b < PREP_XBLK) ? Xbf : Wbf;
    int j = (b < PREP_XBLK) ? (b * 256 + tid) : ((b - PREP_XBLK) * 256 + tid);
    // j indexes half-slots (4 floats each).
    int slot = j >> 1, half = j & 1;
    int row = slot >> 7, st = slot & 127;
    int sd = (st & ~3) | ((st & 3) ^ ((row >> 1) & 3));
    float4 a = *reinterpret_cast<const float4*>(in + (size_t)j * 4);
    us4 v;
    v[0] = f2bf(a.x); v[1] = f2bf(a.y); v[2] = f2bf(a.z); v[3] = f2bf(a.w);
    *reinterpret_cast<us4*>(out + (size_t)row * 1024 + sd * 8 + half * 4) = v;
  } else {
    // h_term[bb][h] = sum_k hs[bb][k] * Hm[h][k]
    int h = b - (PREP_XBLK + PREP_WBLK);
    Hrow4[tid] = reinterpret_cast<const float4*>(Hm + (size_t)h * 1024)[tid];
    __syncthreads();
    int w = tid >> 6, l = tid & 63;
#pragma unroll 2
    for (int bb = w * 16; bb < w * 16 + 16; ++bb) {
      const float4* hb4 = reinterpret_cast<const float4*>(hs + (size_t)bb * 1024);
      float s = 0.f;
#pragma unroll
      for (int p = 0; p < 4; ++p) {
        float4 x = hb4[l + p * 64];
        float4 y = Hrow4[l + p * 64];
        s += x.x * y.x + x.y * y.y + x.z * y.z + x.w * y.w;
      }
#pragma unroll
      for (int off = 32; off > 0; off >>= 1) s += __shfl_down(s, off, 64);
      if (l == 0) ht[bb * 1024 + h] = s;
    }
  }
}

// ---- main GEMM (UNCHANGED from round 5): C = tanh(A.B^T + ht[m%64][n]) ----
__global__ __launch_bounds__(256, 4) void gemm_tanh(
    const unsigned short* __restrict__ A, const unsigned short* __restrict__ B,
    const float* __restrict__ ht, float* __restrict__ out0,
    float* __restrict__ out1) {
  __shared__ unsigned short As[128 * 32];  // 8 KiB
  __shared__ unsigned short Bs[128 * 32];  // 8 KiB

  // XCD-bijective swizzle (nwg = 2048 % 8 == 0); A-panel sharers co-XCD.
  int bid = blockIdx.x;
  int swz = (bid & 7) * 256 + (bid >> 3);
  int bm = swz >> 3;  // 0..255
  int bn = swz & 7;   // 0..7

  int tid = threadIdx.x;
  int lane = tid & 63, wid = tid >> 6;
  int wr = wid >> 1, wc = wid & 1;
  int fr = lane & 15, kq = lane >> 4;

  // Staging: chunk c in [0,1024) -> row c>>2, stored slot c&3; LDS linear.
  // Source memory is pre-swizzled, so global addresses are linear too.
  int c1 = tid + 256;
  const unsigned short* gA0 =
      A + (size_t)(bm * 128 + (tid >> 2)) * 1024 + (tid & 3) * 8;
  const unsigned short* gA1 =
      A + (size_t)(bm * 128 + (c1 >> 2)) * 1024 + (c1 & 3) * 8;
  const unsigned short* gB0 =
      B + (size_t)(bn * 128 + (tid >> 2)) * 1024 + (tid & 3) * 8;
  const unsigned short* gB1 =
      B + (size_t)(bn * 128 + (c1 >> 2)) * 1024 + (c1 & 3) * 8;

  f32x4 acc[4][4] = {};

  for (int ks = 0; ks < K_D; ks += 32) {
    async16(gA0 + ks, &As[tid * 8]);
    async16(gA1 + ks, &As[c1 * 8]);
    async16(gB0 + ks, &Bs[tid * 8]);
    async16(gB1 + ks, &Bs[c1 * 8]);
    __syncthreads();  // drains vmcnt+lgkmcnt before LDS reads

    bf16x8 af[4], bg[4];
#pragma unroll
    for (int mi = 0; mi < 4; ++mi) {
      int ra = wr * 64 + mi * 16 + fr;
      af[mi] = *reinterpret_cast<const bf16x8*>(
          &As[ra * 32 + (kq ^ ((ra >> 1) & 3)) * 8]);
    }
#pragma unroll
    for (int ni = 0; ni < 4; ++ni) {
      int rb = wc * 64 + ni * 16 + fr;
      bg[ni] = *reinterpret_cast<const bf16x8*>(
          &Bs[rb * 32 + (kq ^ ((rb >> 1) & 3)) * 8]);
    }
#pragma unroll
    for (int mi = 0; mi < 4; ++mi)
#pragma unroll
      for (int ni = 0; ni < 4; ++ni)
        acc[mi][ni] = __builtin_amdgcn_mfma_f32_16x16x32_bf16(
            af[mi], bg[ni], acc[mi][ni], 0, 0, 0);
    __syncthreads();  // before next stage overwrites LDS
  }

  // Epilogue: y = tanh(acc + ht[m%64][n]); out0 always, out1 for last 64 rows.
  const int nbase = bn * 128 + wc * 64;
#pragma unroll
  for (int mi = 0; mi < 4; ++mi) {
#pragma unroll
    for (int r = 0; r < 4; ++r) {
      int mloc = wr * 64 + mi * 16 + kq * 4 + r;
      size_t m = (size_t)bm * 128 + mloc;
      int b = mloc & 63;
#pragma unroll
      for (int ni = 0; ni < 4; ++ni) {
        int n = nbase + ni * 16 + fr;
        float x = acc[mi][ni][r] + ht[b * 1024 + n];
        float e = __expf(2.0f * x);
        float y = 1.0f - 2.0f / (e + 1.0f);  // tanh(x), safe at +-inf
        out0[m * 1024 + n] = y;
        if (m >= (size_t)(M_TOT - 64))
          out1[(m - (M_TOT - 64)) * 1024 + n] = y;
      }
    }
  }
}

extern "C" void kernel_launch(void* const* d_in, const int* in_sizes, int n_in,
                              void* d_out, int out_size, void* d_ws,
                              size_t ws_size, hipStream_t stream) {
  (void)in_sizes; (void)n_in; (void)out_size; (void)ws_size;
  const float* X  = (const float*)d_in[0];  // [512,64,1024] = [32768,1024]
  const float* hs = (const float*)d_in[1];  // [64,1024]
  const float* W  = (const float*)d_in[2];  // [1024,1024]
  const float* Hm = (const float*)d_in[3];  // [1024,1024]
  float* out0 = (float*)d_out;               // [32768,1024]
  float* out1 = out0 + (size_t)M_TOT * N_D;  // [64,1024]

  // ws layout: Xbf (64 MiB) | Wbf (2 MiB) | hterm (256 KiB)
  unsigned short* Xbf = (unsigned short*)d_ws;
  unsigned short* Wbf = Xbf + (size_t)M_TOT * K_D;
  float* hterm = (float*)(Wbf + (size_t)N_D * K_D);

  prep_kernel<<<PREP_GRID, 256, 0, stream>>>(X, Xbf, W, Wbf, hs, Hm, hterm);
  gemm_tanh<<<(M_TOT / 128) * (N_D / 128), 256, 0, stream>>>(Xbf, Wbf, hterm,
                                                             out0, out1);
}